// Round 1
// baseline (1810.188 us; speedup 1.0000x reference)
//
#include <hip/hip_runtime.h>
#include <math.h>

#define BB 32
#define NN 1024
#define FF 64
#define PP 128
#define KNN 16
#define H2 256  // 2P
#define F2 128  // 2F

__device__ __forceinline__ float gelu_exact(float x) {
    return 0.5f * x * (1.0f + erff(x * 0.70710678118654752f));
}

// ---------------- Kernel A: exact-order kNN (top-17 incl. self, drop rank 0) ----------
__global__ __launch_bounds__(64) void knn_kernel(const float* __restrict__ points,
                                                 int* __restrict__ idx_out) {
    __shared__ float px[NN], py[NN], pz[NN], rr[NN];
    const int b  = blockIdx.x >> 4;
    const int n0 = (blockIdx.x & 15) * 64;
    const int t  = threadIdx.x;
    const float* pb = points + (size_t)b * NN * 3;
    for (int i = t; i < NN * 3; i += 64) {
        float v = pb[i];
        int n = i / 3, d = i - n * 3;
        if (d == 0) px[n] = v; else if (d == 1) py[n] = v; else pz[n] = v;
    }
    __syncthreads();
    for (int i = t; i < NN; i += 64) {
        float x = px[i], y = py[i], z = pz[i];
        // match numpy: (x*x + y*y) + z*z, no fma contraction
        rr[i] = __fadd_rn(__fadd_rn(__fmul_rn(x, x), __fmul_rn(y, y)), __fmul_rn(z, z));
    }
    __syncthreads();

    const int n = n0 + t;
    const float xn = px[n], yn = py[n], zn = pz[n], rn = rr[n];

    float bd[17]; int bi[17];
#pragma unroll
    for (int j = 0; j < 17; ++j) { bd[j] = 3.4e38f; bi[j] = -1; }

    for (int m = 0; m < NN; ++m) {
        // match numpy: dot = (x*x' + y*y') + z*z'; D = ((rn - 2*dot) + rm) + 1e-5
        float dot = __fadd_rn(__fadd_rn(__fmul_rn(xn, px[m]), __fmul_rn(yn, py[m])),
                              __fmul_rn(zn, pz[m]));
        float D = __fadd_rn(__fadd_rn(__fsub_rn(rn, __fmul_rn(2.0f, dot)), rr[m]), 1e-5f);
        // strict <: equal-distance keeps incumbent (smaller index) -> stable like top_k
        if (D < bd[16]) {
            bd[16] = D; bi[16] = m;
#pragma unroll
            for (int j = 16; j >= 1; --j) {
                if (bd[j] < bd[j - 1]) {
                    float td = bd[j]; bd[j] = bd[j - 1]; bd[j - 1] = td;
                    int   ti = bi[j]; bi[j] = bi[j - 1]; bi[j - 1] = ti;
                }
            }
        }
    }
    int* o = idx_out + ((size_t)b * NN + n) * KNN;
#pragma unroll
    for (int j = 0; j < KNN; ++j) o[j] = bi[j + 1];  // drop rank 0 (self)
}

// ---------------- Kernel B: gather + MLP(gelu) + mean over K, one query per block ----
__global__ __launch_bounds__(256) void mlp_kernel(const float* __restrict__ features,
                                                  const int* __restrict__ knn_idx,
                                                  const float* __restrict__ W1,
                                                  const float* __restrict__ b1,
                                                  const float* __restrict__ W2,
                                                  const float* __restrict__ b2,
                                                  float* __restrict__ out) {
    __shared__ float Xs[KNN][F2];   // 16 x 128 = 8 KB
    __shared__ float Hs[KNN][H2];   // 16 x 256 = 16 KB
    __shared__ float fc[FF];

    const int q = blockIdx.x;
    const int b = q >> 10, n = q & 1023;
    const int t = threadIdx.x;

    if (t < FF) fc[t] = features[((size_t)b * NN + n) * FF + t];
    __syncthreads();

    {   // build X = [nbr - ctr | ctr]
        int k = t >> 4, l = t & 15;
        int nb = knn_idx[(size_t)q * KNN + k];
        const float4* frow = (const float4*)(features + ((size_t)b * NN + nb) * FF);
        float4 v = frow[l];
        float4 c = ((const float4*)fc)[l];
        float4 d; d.x = v.x - c.x; d.y = v.y - c.y; d.z = v.z - c.z; d.w = v.w - c.w;
        ((float4*)&Xs[k][0])[l]  = d;
        ((float4*)&Xs[k][FF])[l] = c;
    }
    __syncthreads();

    const int wv = t >> 6, lane = t & 63;

    {   // layer 1: thread owns hidden col c, all 16 rows
        const int c = wv * 64 + lane;
        float acc[KNN];
#pragma unroll
        for (int k = 0; k < KNN; ++k) acc[k] = 0.f;
        for (int f4 = 0; f4 < F2 / 4; ++f4) {
            float w0 = W1[(4 * f4 + 0) * H2 + c];
            float w1 = W1[(4 * f4 + 1) * H2 + c];
            float w2 = W1[(4 * f4 + 2) * H2 + c];
            float w3 = W1[(4 * f4 + 3) * H2 + c];
#pragma unroll
            for (int k = 0; k < KNN; ++k) {
                float4 x = ((const float4*)&Xs[k][0])[f4];   // LDS broadcast
                acc[k] += x.x * w0 + x.y * w1 + x.z * w2 + x.w * w3;
            }
        }
        float bb = b1[c];
#pragma unroll
        for (int k = 0; k < KNN; ++k) Hs[k][c] = gelu_exact(acc[k] + bb);
    }
    __syncthreads();

    {   // layer 2: thread owns out col c, 8 rows; pair (lane, lane^32) covers 16 rows
        const int c  = wv * 32 + (lane & 31);
        const int k0 = (lane >> 5) * 8;
        float acc[8];
#pragma unroll
        for (int k = 0; k < 8; ++k) acc[k] = 0.f;
        for (int h4 = 0; h4 < H2 / 4; ++h4) {
            float w0 = W2[(4 * h4 + 0) * PP + c];
            float w1 = W2[(4 * h4 + 1) * PP + c];
            float w2 = W2[(4 * h4 + 2) * PP + c];
            float w3 = W2[(4 * h4 + 3) * PP + c];
#pragma unroll
            for (int k = 0; k < 8; ++k) {
                float4 x = ((const float4*)&Hs[k0 + k][0])[h4];  // LDS broadcast (2 addrs)
                acc[k] += x.x * w0 + x.y * w1 + x.z * w2 + x.w * w3;
            }
        }
        float bb = b2[c];
        float s = 0.f;
#pragma unroll
        for (int k = 0; k < 8; ++k) s += gelu_exact(acc[k] + bb);
        s += __shfl_xor(s, 32, 64);
        if (lane < 32) out[((size_t)b * NN + n) * PP + c] = s * 0.0625f;
    }
}

extern "C" void kernel_launch(void* const* d_in, const int* in_sizes, int n_in,
                              void* d_out, int out_size, void* d_ws, size_t ws_size,
                              hipStream_t stream) {
    const float* points   = (const float*)d_in[0];
    const float* features = (const float*)d_in[1];
    const float* W1 = (const float*)d_in[2];
    const float* b1 = (const float*)d_in[3];
    const float* W2 = (const float*)d_in[4];
    const float* b2 = (const float*)d_in[5];
    float* out = (float*)d_out;
    int* knn_idx = (int*)d_ws;  // 32*1024*16*4 = 2 MB scratch

    knn_kernel<<<BB * 16, 64, 0, stream>>>(points, knn_idx);
    mlp_kernel<<<BB * NN, 256, 0, stream>>>(features, knn_idx, W1, b1, W2, b2, out);
}

// Round 2
// 462.414 us; speedup vs baseline: 3.9146x; 3.9146x over previous
//
#include <hip/hip_runtime.h>
#include <math.h>

#define BB 32
#define NN 1024
#define FF 64
#define PP 128
#define KNN 16
#define H2 256  // 2P
#define F2 128  // 2F

typedef float f32x4 __attribute__((ext_vector_type(4)));
typedef __bf16 bf16x8 __attribute__((ext_vector_type(8)));

__device__ __forceinline__ float gelu_fast(float x) {
    // tanh-approx gelu; |err vs exact| <= ~3e-4, far under the 7.5e-2 threshold.
    float u = x * (1.0f + 0.044715f * x * x);            // x + 0.044715 x^3
    float e = __builtin_amdgcn_exp2f(-2.3022115f * u);   // exp(-2*0.7978845608*u)
    return x * __builtin_amdgcn_rcpf(1.0f + e);          // x * sigmoid(2*0.79788*u)
}

// ---------------- Kernel A: exact-order kNN (top-17 incl. self, drop rank 0) ----------
__global__ __launch_bounds__(64) void knn_kernel(const float* __restrict__ points,
                                                 int* __restrict__ idx_out) {
    __shared__ float px[NN], py[NN], pz[NN], rr[NN];
    const int b  = blockIdx.x >> 4;
    const int n0 = (blockIdx.x & 15) * 64;
    const int t  = threadIdx.x;
    const float* pb = points + (size_t)b * NN * 3;
    for (int i = t; i < NN * 3; i += 64) {
        float v = pb[i];
        int n = i / 3, d = i - n * 3;
        if (d == 0) px[n] = v; else if (d == 1) py[n] = v; else pz[n] = v;
    }
    __syncthreads();
    for (int i = t; i < NN; i += 64) {
        float x = px[i], y = py[i], z = pz[i];
        rr[i] = __fadd_rn(__fadd_rn(__fmul_rn(x, x), __fmul_rn(y, y)), __fmul_rn(z, z));
    }
    __syncthreads();

    const int n = n0 + t;
    const float xn = px[n], yn = py[n], zn = pz[n], rn = rr[n];

    float bd[17]; int bi[17];
#pragma unroll
    for (int j = 0; j < 17; ++j) { bd[j] = 3.4e38f; bi[j] = -1; }

    for (int m = 0; m < NN; ++m) {
        float dot = __fadd_rn(__fadd_rn(__fmul_rn(xn, px[m]), __fmul_rn(yn, py[m])),
                              __fmul_rn(zn, pz[m]));
        float D = __fadd_rn(__fadd_rn(__fsub_rn(rn, __fmul_rn(2.0f, dot)), rr[m]), 1e-5f);
        if (D < bd[16]) {
            bd[16] = D; bi[16] = m;
#pragma unroll
            for (int j = 16; j >= 1; --j) {
                if (bd[j] < bd[j - 1]) {
                    float td = bd[j]; bd[j] = bd[j - 1]; bd[j - 1] = td;
                    int   ti = bi[j]; bi[j] = bi[j - 1]; bi[j - 1] = ti;
                }
            }
        }
    }
    int* o = idx_out + ((size_t)b * NN + n) * KNN;
#pragma unroll
    for (int j = 0; j < KNN; ++j) o[j] = bi[j + 1];
}

// ---------------- Kernel P: weight transpose + bf16 cast --------------------------
// W1 [128][256] (f,h) -> W1t [256][128] (h,f);  W2 [256][128] (h,p) -> W2t [128][256] (p,h)
__global__ __launch_bounds__(256) void prep_weights(const float* __restrict__ W1,
                                                    const float* __restrict__ W2,
                                                    __bf16* __restrict__ W1t,
                                                    __bf16* __restrict__ W2t) {
    int t = blockIdx.x * 256 + threadIdx.x;   // 0 .. 32767
    {   int f = t >> 8, h = t & 255;          // W1 flat index t = f*256+h
        W1t[h * F2 + f] = (__bf16)W1[t]; }
    {   int h = t >> 7, p = t & 127;          // W2 flat index t = h*128+p
        W2t[p * H2 + h] = (__bf16)W2[t]; }
}

// ---------------- Kernel B: MFMA gather+MLP+mean. 1 block = 4 queries = 64 rows -----
// LDS rows padded to 136 bf16 (272 B): bank-step 4 -> 2-way conflict (free).
#define XPITCH 136

__global__ __launch_bounds__(256) void mlp_mfma(const float* __restrict__ features,
                                                const int* __restrict__ knn_idx,
                                                const __bf16* __restrict__ W1t,
                                                const float* __restrict__ b1,
                                                const __bf16* __restrict__ W2t,
                                                const float* __restrict__ b2,
                                                float* __restrict__ out) {
    __shared__ __bf16 Xs[64][XPITCH];   // 17.0 KB   X = [nbr-ctr | ctr], 64x128
    __shared__ __bf16 Hs[64][XPITCH];   // 17.0 KB   current hidden half, 64x128

    const int t    = threadIdx.x;
    const int w    = t >> 6;        // wave 0..3
    const int lane = t & 63;
    const int quad = lane >> 4;
    const int l16  = lane & 15;
    const int gq0  = blockIdx.x * 4;        // first global query (b*1024+n)
    const int b    = gq0 >> 10;

    // ---- gather X ----
    {
        const int r  = t >> 2;               // 0..63
        const int ql = r >> 4, k = r & 15;
        const int gq = gq0 + ql;
        const int nq = gq & 1023;
        const int nb = knn_idx[gq * KNN + k];
        const float* nrow = features + ((size_t)b * NN + nb) * FF;
        const float* crow = features + ((size_t)b * NN + nq) * FF;
        const int f0 = (t & 3) * 16;
#pragma unroll
        for (int i = 0; i < 4; ++i) {
            float4 nv = *(const float4*)(nrow + f0 + i * 4);
            float4 cv = *(const float4*)(crow + f0 + i * 4);
            Xs[r][f0 + i*4 + 0] = (__bf16)(nv.x - cv.x);
            Xs[r][f0 + i*4 + 1] = (__bf16)(nv.y - cv.y);
            Xs[r][f0 + i*4 + 2] = (__bf16)(nv.z - cv.z);
            Xs[r][f0 + i*4 + 3] = (__bf16)(nv.w - cv.w);
            Xs[r][FF + f0 + i*4 + 0] = (__bf16)cv.x;
            Xs[r][FF + f0 + i*4 + 1] = (__bf16)cv.y;
            Xs[r][FF + f0 + i*4 + 2] = (__bf16)cv.z;
            Xs[r][FF + f0 + i*4 + 3] = (__bf16)cv.w;
        }
    }
    __syncthreads();

    const int ncol0 = w * 32;   // this wave's 32-col output strip (both layers)

    f32x4 acc2[4][2];
#pragma unroll
    for (int tm = 0; tm < 4; ++tm)
#pragma unroll
        for (int nt = 0; nt < 2; ++nt) acc2[tm][nt] = (f32x4){0.f, 0.f, 0.f, 0.f};

#pragma unroll
    for (int half = 0; half < 2; ++half) {
        const int hbase = half * PP;   // hidden-col base (0 or 128)

        // ---- layer 1: C1 = X(64x128) @ W1[:, hbase+ncol0 .. +32] ----
        f32x4 acc1[4][2];
#pragma unroll
        for (int tm = 0; tm < 4; ++tm)
#pragma unroll
            for (int nt = 0; nt < 2; ++nt) acc1[tm][nt] = (f32x4){0.f, 0.f, 0.f, 0.f};

#pragma unroll
        for (int kk = 0; kk < 4; ++kk) {
            bf16x8 a[4];
#pragma unroll
            for (int tm = 0; tm < 4; ++tm)
                a[tm] = *(const bf16x8*)&Xs[tm * 16 + l16][kk * 32 + quad * 8];
            bf16x8 bb[2];
#pragma unroll
            for (int nt = 0; nt < 2; ++nt) {
                int n = hbase + ncol0 + nt * 16 + l16;
                bb[nt] = *(const bf16x8*)(W1t + (size_t)n * F2 + kk * 32 + quad * 8);
            }
#pragma unroll
            for (int tm = 0; tm < 4; ++tm)
#pragma unroll
                for (int nt = 0; nt < 2; ++nt)
                    acc1[tm][nt] = __builtin_amdgcn_mfma_f32_16x16x32_bf16(
                        a[tm], bb[nt], acc1[tm][nt], 0, 0, 0);
        }

        // ---- epilogue 1: bias + gelu -> Hs (bf16) ----
#pragma unroll
        for (int nt = 0; nt < 2; ++nt) {
            float bias = b1[hbase + ncol0 + nt * 16 + l16];
#pragma unroll
            for (int tm = 0; tm < 4; ++tm)
#pragma unroll
                for (int r = 0; r < 4; ++r) {
                    float v = acc1[tm][nt][r] + bias;
                    Hs[tm * 16 + quad * 4 + r][ncol0 + nt * 16 + l16] = (__bf16)gelu_fast(v);
                }
        }
        __syncthreads();

        // ---- layer 2 partial: acc2 += H_half(64x128) @ W2[hbase.. , ncol0..+32] ----
#pragma unroll
        for (int kk = 0; kk < 4; ++kk) {
            bf16x8 a[4];
#pragma unroll
            for (int tm = 0; tm < 4; ++tm)
                a[tm] = *(const bf16x8*)&Hs[tm * 16 + l16][kk * 32 + quad * 8];
            bf16x8 bb[2];
#pragma unroll
            for (int nt = 0; nt < 2; ++nt) {
                int p = ncol0 + nt * 16 + l16;
                bb[nt] = *(const bf16x8*)(W2t + (size_t)p * H2 + hbase + kk * 32 + quad * 8);
            }
#pragma unroll
            for (int tm = 0; tm < 4; ++tm)
#pragma unroll
                for (int nt = 0; nt < 2; ++nt)
                    acc2[tm][nt] = __builtin_amdgcn_mfma_f32_16x16x32_bf16(
                        a[tm], bb[nt], acc2[tm][nt], 0, 0, 0);
        }
        __syncthreads();   // Hs reused next half
    }

    // ---- final epilogue: bias + gelu + mean over 16 neighbors (tile rows) ----
#pragma unroll
    for (int nt = 0; nt < 2; ++nt) {
        const int p = ncol0 + nt * 16 + l16;
        const float bias = b2[p];
#pragma unroll
        for (int tm = 0; tm < 4; ++tm) {
            float s = 0.f;
#pragma unroll
            for (int r = 0; r < 4; ++r) s += gelu_fast(acc2[tm][nt][r] + bias);
            s += __shfl_xor(s, 16, 64);   // quads 0+1, 2+3
            s += __shfl_xor(s, 32, 64);   // all 16 rows
            if (quad == 0) {
                int gq = gq0 + tm;        // == b*1024 + n
                out[(size_t)gq * PP + p] = s * 0.0625f;
            }
        }
    }
}

extern "C" void kernel_launch(void* const* d_in, const int* in_sizes, int n_in,
                              void* d_out, int out_size, void* d_ws, size_t ws_size,
                              hipStream_t stream) {
    const float* points   = (const float*)d_in[0];
    const float* features = (const float*)d_in[1];
    const float* W1 = (const float*)d_in[2];
    const float* b1 = (const float*)d_in[3];
    const float* W2 = (const float*)d_in[4];
    const float* b2 = (const float*)d_in[5];
    float* out = (float*)d_out;

    int* knn_idx = (int*)d_ws;                                   // 2 MB
    __bf16* W1t  = (__bf16*)((char*)d_ws + (size_t)BB*NN*KNN*4); // 64 KB
    __bf16* W2t  = W1t + H2 * F2;                                // 64 KB

    prep_weights<<<128, 256, 0, stream>>>(W1, W2, W1t, W2t);
    knn_kernel<<<BB * 16, 64, 0, stream>>>(points, knn_idx);
    mlp_mfma<<<BB * NN / 4, 256, 0, stream>>>(features, knn_idx, W1t, b1, W2t, b2, out);
}

// Round 3
// 258.646 us; speedup vs baseline: 6.9987x; 1.7878x over previous
//
#include <hip/hip_runtime.h>
#include <math.h>

#define BB 32
#define NN 1024
#define FF 64
#define PP 128
#define KNN 16
#define H2 256  // 2P
#define F2 128  // 2F
#define KSEL 17
#define SVCAP 272   // hard cap: 17 lanes * 16 candidates

typedef float f32x4 __attribute__((ext_vector_type(4)));
typedef __bf16 bf16x8 __attribute__((ext_vector_type(8)));

__device__ __forceinline__ float gelu_fast(float x) {
    float u = x * (1.0f + 0.044715f * x * x);
    float e = __builtin_amdgcn_exp2f(-2.3022115f * u);
    return x * __builtin_amdgcn_rcpf(1.0f + e);
}

// ---------------- Kernel A: set-based kNN via radix ballot-select -------------------
// One wave per query. Output: the top-17-by-(D,idx) set minus its lexicographic min
// (== numpy rank 0), order-free (mean over K is order-invariant).
__global__ __launch_bounds__(512, 8) void knn_select(const float* __restrict__ points,
                                                     int* __restrict__ idx_out) {
    __shared__ float4 pts[NN];            // 16 KB {x,y,z,r}
    __shared__ unsigned sv_val[8][SVCAP]; // 8.5 KB
    __shared__ unsigned sv_idx[8][SVCAP]; // 8.5 KB
    __shared__ unsigned tie_idx[8][64];   // 2 KB
    __shared__ unsigned lcnt[8], wcnt[8], tcnt[8];

    const int t = threadIdx.x;
    const int w = t >> 6, lane = t & 63;
    const int b = blockIdx.x >> 7;            // 128 blocks per batch
    const int q0 = (blockIdx.x & 127) * 8;    // first local query of this block
    const float* pb = points + (size_t)b * NN * 3;

    for (int i = t; i < NN; i += 512) {
        float x = pb[3 * i], y = pb[3 * i + 1], z = pb[3 * i + 2];
        float r = __fadd_rn(__fadd_rn(__fmul_rn(x, x), __fmul_rn(y, y)), __fmul_rn(z, z));
        pts[i] = make_float4(x, y, z, r);
    }
    if (t < 8) { lcnt[t] = 0; wcnt[t] = 0; tcnt[t] = 0; }
    __syncthreads();

    const int qn = q0 + w;                    // local query index 0..1023
    const int gq = b * NN + qn;
    const float4 qp = pts[qn];

    // ---- exact distances (bit-identical to numpy formula) ----
    float D[16];
#pragma unroll
    for (int j = 0; j < 16; ++j) {
        float4 c = pts[j * 64 + lane];
        float dot = __fadd_rn(__fadd_rn(__fmul_rn(qp.x, c.x), __fmul_rn(qp.y, c.y)),
                              __fmul_rn(qp.z, c.z));
        D[j] = __fadd_rn(__fadd_rn(__fsub_rn(qp.w, __fmul_rn(2.0f, dot)), c.w), 1e-5f);
    }

    // ---- lane-min, then T_ub = 17th smallest lane-min (radix ballot search) ----
    float mnf = D[0];
#pragma unroll
    for (int j = 1; j < 16; ++j) mnf = fminf(mnf, D[j]);
    const unsigned mbits = __float_as_uint(mnf);  // positive floats: bit order == value order

    unsigned T = 0;
#pragma unroll
    for (int bit = 31; bit >= 0; --bit) {
        unsigned cand = T | (1u << bit);
        int cnt = __popcll(__ballot(mbits < cand));
        if (cnt < KSEL) T = cand;   // max T with #{x<T} <= 16  ->  T = 17th smallest
    }

    // ---- compact survivors (value <= T_ub): superset of the top-17 ----
#pragma unroll
    for (int j = 0; j < 16; ++j) {
        unsigned vb = __float_as_uint(D[j]);
        if (vb <= T) {
            unsigned pos = atomicAdd(&lcnt[w], 1u);
            if (pos < SVCAP) { sv_val[w][pos] = vb; sv_idx[w][pos] = j * 64 + lane; }
        }
    }
    unsigned C = lcnt[w];
    if (C > SVCAP) C = SVCAP;
    const int S = (int)((C + 63) >> 6);       // chunks, wave-uniform, <= 5

    // ---- T* = exact 17th smallest survivor value ----
    unsigned xv0 = (lane < (int)C) ? sv_val[w][lane] : 0xFFFFFFFFu;
    unsigned Ts = 0;
    if (S == 1) {
#pragma unroll
        for (int bit = 31; bit >= 0; --bit) {
            unsigned cand = Ts | (1u << bit);
            int cnt = __popcll(__ballot(xv0 < cand));
            if (cnt < KSEL) Ts = cand;
        }
    } else {
        for (int bit = 31; bit >= 0; --bit) {
            unsigned cand = Ts | (1u << bit);
            int cnt = 0;
            for (int s = 0; s < S; ++s) {
                int i = s * 64 + lane;
                unsigned vb = (i < (int)C) ? sv_val[w][i] : 0xFFFFFFFFu;
                cnt += __popcll(__ballot(vb < cand));
            }
            if (cnt < KSEL) Ts = cand;
        }
    }

    // ---- L = #{ < T* };  need = ties to take at T* (stable: smallest indices) ----
    int L = 0;
    for (int s = 0; s < S; ++s) {
        int i = s * 64 + lane;
        unsigned vb = (i < (int)C) ? sv_val[w][i] : 0xFFFFFFFFu;
        L += __popcll(__ballot(vb < Ts));
    }
    const int need = KSEL - L;   // >= 1 always

    // ---- dropIdx = lexicographic-min (val, idx) of the top-17 == numpy rank 0 ----
    unsigned vmin_l = 0xFFFFFFFFu;
    for (int s = 0; s < S; ++s) {
        int i = s * 64 + lane;
        unsigned vb = (i < (int)C) ? sv_val[w][i] : 0xFFFFFFFFu;
        vmin_l = vmin_l < vb ? vmin_l : vb;
    }
#pragma unroll
    for (int off = 32; off >= 1; off >>= 1) {
        unsigned o = __shfl_xor(vmin_l, off, 64);
        vmin_l = vmin_l < o ? vmin_l : o;
    }
    const unsigned Vmin = vmin_l;
    unsigned imin_l = 0xFFFFFFFFu;
    for (int s = 0; s < S; ++s) {
        int i = s * 64 + lane;
        unsigned vb = (i < (int)C) ? sv_val[w][i] : 0xFFFFFFFFu;
        unsigned mi = (i < (int)C) ? sv_idx[w][i] : 0xFFFFFFFFu;
        if (vb == Vmin && mi < imin_l) imin_l = mi;
    }
#pragma unroll
    for (int off = 32; off >= 1; off >>= 1) {
        unsigned o = __shfl_xor(imin_l, off, 64);
        imin_l = imin_l < o ? imin_l : o;
    }
    const unsigned dropIdx = imin_l;

    // ---- write sure-includes (< T*) except drop; collect ties (== T*) ----
    int* o = idx_out + (size_t)gq * KNN;
    for (int s = 0; s < S; ++s) {
        int i = s * 64 + lane;
        unsigned vb = (i < (int)C) ? sv_val[w][i] : 0xFFFFFFFFu;
        unsigned mi = (i < (int)C) ? sv_idx[w][i] : 0u;
        if (vb < Ts && mi != dropIdx) {
            unsigned pos = atomicAdd(&wcnt[w], 1u);
            o[pos] = (int)mi;
        }
        if (vb == Ts) {
            unsigned tp = atomicAdd(&tcnt[w], 1u);
            if (tp < 64) tie_idx[w][tp] = mi;
        }
    }
    unsigned tc = tcnt[w];
    if (tc > 64) tc = 64;
    if ((int)tc == need) {                    // common case: take all ties
        if (lane < (int)tc) {
            unsigned mi = tie_idx[w][lane];
            if (mi != dropIdx) {
                unsigned pos = atomicAdd(&wcnt[w], 1u);
                o[pos] = (int)mi;
            }
        }
    } else if (lane == 0) {                   // rare: pick `need` smallest tie indices
        for (int r = 0; r < need; ++r) {
            unsigned best = 0xFFFFFFFFu; int bj = 0;
            for (int j2 = 0; j2 < (int)tc; ++j2) {
                unsigned mi = tie_idx[w][j2];
                if (mi < best) { best = mi; bj = j2; }
            }
            tie_idx[w][bj] = 0xFFFFFFFFu;
            if (best != dropIdx) {
                unsigned pos = atomicAdd(&wcnt[w], 1u);
                o[pos] = (int)best;
            }
        }
    }
}

// ---------------- Kernel P: weight transpose + bf16 cast --------------------------
__global__ __launch_bounds__(256) void prep_weights(const float* __restrict__ W1,
                                                    const float* __restrict__ W2,
                                                    __bf16* __restrict__ W1t,
                                                    __bf16* __restrict__ W2t) {
    int t = blockIdx.x * 256 + threadIdx.x;
    {   int f = t >> 8, h = t & 255;
        W1t[h * F2 + f] = (__bf16)W1[t]; }
    {   int h = t >> 7, p = t & 127;
        W2t[p * H2 + h] = (__bf16)W2[t]; }
}

// ---------------- Kernel B: MFMA gather+MLP+mean (unchanged from R2) ----------------
#define XPITCH 136

__global__ __launch_bounds__(256) void mlp_mfma(const float* __restrict__ features,
                                                const int* __restrict__ knn_idx,
                                                const __bf16* __restrict__ W1t,
                                                const float* __restrict__ b1,
                                                const __bf16* __restrict__ W2t,
                                                const float* __restrict__ b2,
                                                float* __restrict__ out) {
    __shared__ __bf16 Xs[64][XPITCH];
    __shared__ __bf16 Hs[64][XPITCH];

    const int t    = threadIdx.x;
    const int w    = t >> 6;
    const int lane = t & 63;
    const int quad = lane >> 4;
    const int l16  = lane & 15;
    const int gq0  = blockIdx.x * 4;
    const int b    = gq0 >> 10;

    {
        const int r  = t >> 2;
        const int ql = r >> 4, k = r & 15;
        const int gq = gq0 + ql;
        const int nq = gq & 1023;
        const int nb = knn_idx[gq * KNN + k];
        const float* nrow = features + ((size_t)b * NN + nb) * FF;
        const float* crow = features + ((size_t)b * NN + nq) * FF;
        const int f0 = (t & 3) * 16;
#pragma unroll
        for (int i = 0; i < 4; ++i) {
            float4 nv = *(const float4*)(nrow + f0 + i * 4);
            float4 cv = *(const float4*)(crow + f0 + i * 4);
            Xs[r][f0 + i*4 + 0] = (__bf16)(nv.x - cv.x);
            Xs[r][f0 + i*4 + 1] = (__bf16)(nv.y - cv.y);
            Xs[r][f0 + i*4 + 2] = (__bf16)(nv.z - cv.z);
            Xs[r][f0 + i*4 + 3] = (__bf16)(nv.w - cv.w);
            Xs[r][FF + f0 + i*4 + 0] = (__bf16)cv.x;
            Xs[r][FF + f0 + i*4 + 1] = (__bf16)cv.y;
            Xs[r][FF + f0 + i*4 + 2] = (__bf16)cv.z;
            Xs[r][FF + f0 + i*4 + 3] = (__bf16)cv.w;
        }
    }
    __syncthreads();

    const int ncol0 = w * 32;

    f32x4 acc2[4][2];
#pragma unroll
    for (int tm = 0; tm < 4; ++tm)
#pragma unroll
        for (int nt = 0; nt < 2; ++nt) acc2[tm][nt] = (f32x4){0.f, 0.f, 0.f, 0.f};

#pragma unroll
    for (int half = 0; half < 2; ++half) {
        const int hbase = half * PP;

        f32x4 acc1[4][2];
#pragma unroll
        for (int tm = 0; tm < 4; ++tm)
#pragma unroll
            for (int nt = 0; nt < 2; ++nt) acc1[tm][nt] = (f32x4){0.f, 0.f, 0.f, 0.f};

#pragma unroll
        for (int kk = 0; kk < 4; ++kk) {
            bf16x8 a[4];
#pragma unroll
            for (int tm = 0; tm < 4; ++tm)
                a[tm] = *(const bf16x8*)&Xs[tm * 16 + l16][kk * 32 + quad * 8];
            bf16x8 bb[2];
#pragma unroll
            for (int nt = 0; nt < 2; ++nt) {
                int n = hbase + ncol0 + nt * 16 + l16;
                bb[nt] = *(const bf16x8*)(W1t + (size_t)n * F2 + kk * 32 + quad * 8);
            }
#pragma unroll
            for (int tm = 0; tm < 4; ++tm)
#pragma unroll
                for (int nt = 0; nt < 2; ++nt)
                    acc1[tm][nt] = __builtin_amdgcn_mfma_f32_16x16x32_bf16(
                        a[tm], bb[nt], acc1[tm][nt], 0, 0, 0);
        }

#pragma unroll
        for (int nt = 0; nt < 2; ++nt) {
            float bias = b1[hbase + ncol0 + nt * 16 + l16];
#pragma unroll
            for (int tm = 0; tm < 4; ++tm)
#pragma unroll
                for (int r = 0; r < 4; ++r) {
                    float v = acc1[tm][nt][r] + bias;
                    Hs[tm * 16 + quad * 4 + r][ncol0 + nt * 16 + l16] = (__bf16)gelu_fast(v);
                }
        }
        __syncthreads();

#pragma unroll
        for (int kk = 0; kk < 4; ++kk) {
            bf16x8 a[4];
#pragma unroll
            for (int tm = 0; tm < 4; ++tm)
                a[tm] = *(const bf16x8*)&Hs[tm * 16 + l16][kk * 32 + quad * 8];
            bf16x8 bb[2];
#pragma unroll
            for (int nt = 0; nt < 2; ++nt) {
                int p = ncol0 + nt * 16 + l16;
                bb[nt] = *(const bf16x8*)(W2t + (size_t)p * H2 + hbase + kk * 32 + quad * 8);
            }
#pragma unroll
            for (int tm = 0; tm < 4; ++tm)
#pragma unroll
                for (int nt = 0; nt < 2; ++nt)
                    acc2[tm][nt] = __builtin_amdgcn_mfma_f32_16x16x32_bf16(
                        a[tm], bb[nt], acc2[tm][nt], 0, 0, 0);
        }
        __syncthreads();
    }

#pragma unroll
    for (int nt = 0; nt < 2; ++nt) {
        const int p = ncol0 + nt * 16 + l16;
        const float bias = b2[p];
#pragma unroll
        for (int tm = 0; tm < 4; ++tm) {
            float s = 0.f;
#pragma unroll
            for (int r = 0; r < 4; ++r) s += gelu_fast(acc2[tm][nt][r] + bias);
            s += __shfl_xor(s, 16, 64);
            s += __shfl_xor(s, 32, 64);
            if (quad == 0) {
                int gq = gq0 + tm;
                out[(size_t)gq * PP + p] = s * 0.0625f;
            }
        }
    }
}

extern "C" void kernel_launch(void* const* d_in, const int* in_sizes, int n_in,
                              void* d_out, int out_size, void* d_ws, size_t ws_size,
                              hipStream_t stream) {
    const float* points   = (const float*)d_in[0];
    const float* features = (const float*)d_in[1];
    const float* W1 = (const float*)d_in[2];
    const float* b1 = (const float*)d_in[3];
    const float* W2 = (const float*)d_in[4];
    const float* b2 = (const float*)d_in[5];
    float* out = (float*)d_out;

    int* knn_idx = (int*)d_ws;                                   // 2 MB
    __bf16* W1t  = (__bf16*)((char*)d_ws + (size_t)BB*NN*KNN*4); // 64 KB
    __bf16* W2t  = W1t + H2 * F2;                                // 64 KB

    prep_weights<<<128, 256, 0, stream>>>(W1, W2, W1t, W2t);
    knn_select<<<BB * 128, 512, 0, stream>>>(points, knn_idx);
    mlp_mfma<<<BB * NN / 4, 256, 0, stream>>>(features, knn_idx, W1t, b1, W2t, b2, out);
}